// Round 1
// baseline (81.498 us; speedup 1.0000x reference)
//
#include <hip/hip_runtime.h>

// out[b,u] = prod_i ( x[b,i]*w[i,u] + (1 - w[i,u]) )
// B=2048, IN_DIM=256, UNITS=512
//
// Layout: lane <-> unit u (w loads coalesced 256B/wave); each thread computes
// TB=8 batch rows, so one w load feeds 16 VALU ops. x addresses are
// thread-uniform -> compiler emits s_load (scalar cache), no LDS needed.

#define B_DIM    2048
#define IN_DIM   256
#define UNITS    512
#define TB       8
#define BLOCK    256

__global__ __launch_bounds__(BLOCK) void prodw_kernel(
    const float* __restrict__ x,   // [B, IN_DIM]
    const float* __restrict__ w,   // [IN_DIM, UNITS]
    float* __restrict__ out)       // [B, UNITS]
{
    const int u  = blockIdx.x * BLOCK + threadIdx.x;  // unit index (lane-varying)
    const int b0 = blockIdx.y * TB;                   // batch tile base (uniform)

    const float* __restrict__ xrow = x + (size_t)b0 * IN_DIM;

    float p[TB];
#pragma unroll
    for (int j = 0; j < TB; ++j) p[j] = 1.0f;

#pragma unroll 4
    for (int i = 0; i < IN_DIM; ++i) {
        const float wv = w[(size_t)i * UNITS + u];  // coalesced vector load
        const float c  = 1.0f - wv;                 // 1 VALU per i
#pragma unroll
        for (int j = 0; j < TB; ++j) {
            const float xv = xrow[j * IN_DIM + i];  // uniform -> s_load
            p[j] *= fmaf(xv, wv, c);                // x*w + (1-w)
        }
    }

#pragma unroll
    for (int j = 0; j < TB; ++j)
        out[(size_t)(b0 + j) * UNITS + u] = p[j];   // coalesced store
}

extern "C" void kernel_launch(void* const* d_in, const int* in_sizes, int n_in,
                              void* d_out, int out_size, void* d_ws, size_t ws_size,
                              hipStream_t stream) {
    const float* x = (const float*)d_in[0];        // 2048*256
    const float* w = (const float*)d_in[1];        // 256*512
    float* out     = (float*)d_out;                // 2048*512

    dim3 grid(UNITS / BLOCK, B_DIM / TB);          // (2, 256) = 512 blocks
    dim3 block(BLOCK);
    prodw_kernel<<<grid, block, 0, stream>>>(x, w, out);
}

// Round 2
// 77.159 us; speedup vs baseline: 1.0562x; 1.0562x over previous
//
#include <hip/hip_runtime.h>

// out[b,u] = prod_i ( x[b,i]*w[i,u] + (1 - w[i,u]) )
// B=2048, IN_DIM=256, UNITS=512
//
// Structure: lane <-> unit u (w loads coalesced dword); TB=8 batch rows per
// thread so one w value feeds 16 VALU ops. x tile (8 KB) staged in LDS once,
// read back as ds_read_b128 broadcasts (in-order lgkm -> fine-grained waits,
// zero bank conflicts). w loads software-pipelined one 4-i group ahead.

#define B_DIM    2048
#define IN_DIM   256
#define UNITS    512
#define TB       8
#define BLOCK    256

__global__ __launch_bounds__(BLOCK, 2) void prodw_kernel(
    const float* __restrict__ x,   // [B, IN_DIM]
    const float* __restrict__ w,   // [IN_DIM, UNITS]
    float* __restrict__ out)       // [B, UNITS]
{
    __shared__ __align__(16) float xs[TB * IN_DIM];   // 8 KB

    const int tid = threadIdx.x;
    const int u   = blockIdx.x * BLOCK + tid;         // unit index (lane-varying)
    const int b0  = blockIdx.y * TB;                  // batch tile base (uniform)

    // Stage x tile: TB*IN_DIM = 2048 floats = 512 float4 loads, 2 per thread.
    {
        const float4* __restrict__ xg = (const float4*)(x + (size_t)b0 * IN_DIM);
        float4* xl = (float4*)xs;
        xl[tid]         = xg[tid];
        xl[tid + BLOCK] = xg[tid + BLOCK];
    }
    __syncthreads();

    float p[TB];
#pragma unroll
    for (int j = 0; j < TB; ++j) p[j] = 1.0f;

    const float* __restrict__ wu = w + u;

    // Prefetch group 0's w values.
    float w0 = wu[0 * UNITS];
    float w1 = wu[1 * UNITS];
    float w2 = wu[2 * UNITS];
    float w3 = wu[3 * UNITS];

    // 64 groups of 4 i; prefetch next group's w while computing current.
    for (int g = 0; g < (IN_DIM / 4) - 1; ++g) {
        const int i4 = g * 4;
        const float* __restrict__ wn = wu + (size_t)(i4 + 4) * UNITS;
        const float n0 = wn[0 * UNITS];
        const float n1 = wn[1 * UNITS];
        const float n2 = wn[2 * UNITS];
        const float n3 = wn[3 * UNITS];

        const float c0 = 1.0f - w0;
        const float c1 = 1.0f - w1;
        const float c2 = 1.0f - w2;
        const float c3 = 1.0f - w3;
#pragma unroll
        for (int j = 0; j < TB; ++j) {
            const float4 xq = *(const float4*)&xs[j * IN_DIM + i4];
            const float t0 = fmaf(xq.x, w0, c0);
            const float t1 = fmaf(xq.y, w1, c1);
            const float t2 = fmaf(xq.z, w2, c2);
            const float t3 = fmaf(xq.w, w3, c3);
            p[j] *= (t0 * t1) * (t2 * t3);   // short dep tree into p[j]
        }
        w0 = n0; w1 = n1; w2 = n2; w3 = n3;
    }

    // Epilogue group (i4 = IN_DIM-4), no prefetch (avoids OOB w read).
    {
        const int i4 = IN_DIM - 4;
        const float c0 = 1.0f - w0;
        const float c1 = 1.0f - w1;
        const float c2 = 1.0f - w2;
        const float c3 = 1.0f - w3;
#pragma unroll
        for (int j = 0; j < TB; ++j) {
            const float4 xq = *(const float4*)&xs[j * IN_DIM + i4];
            const float t0 = fmaf(xq.x, w0, c0);
            const float t1 = fmaf(xq.y, w1, c1);
            const float t2 = fmaf(xq.z, w2, c2);
            const float t3 = fmaf(xq.w, w3, c3);
            p[j] *= (t0 * t1) * (t2 * t3);
        }
    }

#pragma unroll
    for (int j = 0; j < TB; ++j)
        out[(size_t)(b0 + j) * UNITS + u] = p[j];    // coalesced dword stores
}

extern "C" void kernel_launch(void* const* d_in, const int* in_sizes, int n_in,
                              void* d_out, int out_size, void* d_ws, size_t ws_size,
                              hipStream_t stream) {
    const float* x = (const float*)d_in[0];        // 2048*256
    const float* w = (const float*)d_in[1];        // 256*512
    float* out     = (float*)d_out;                // 2048*512

    dim3 grid(UNITS / BLOCK, B_DIM / TB);          // (2, 256) = 512 blocks
    dim3 block(BLOCK);
    prodw_kernel<<<grid, block, 0, stream>>>(x, w, out);
}

// Round 3
// 75.878 us; speedup vs baseline: 1.0741x; 1.0169x over previous
//
#include <hip/hip_runtime.h>

// out[b,u] = prod_i ( x[b,i]*w[i,u] + (1 - w[i,u]) )
// B=2048, IN_DIM=256, UNITS=512
//
// Round 3: packed fp32 (v_pk_fma_f32 / v_pk_mul_f32) over i-pairs halves the
// VALU issue count; x rows are block-uniform -> s_load_dwordx4 into SGPRs
// (scalar pipe, no LDS, no VALU); pk_fma(v_w, s_x, v_c) uses exactly 1 SGPR
// source (legal). w (lane-varying, coalesced dword) and x both software-
// pipelined one 4-i group ahead. No LDS at all.

typedef float v2f __attribute__((ext_vector_type(2)));

#define B_DIM    2048
#define IN_DIM   256
#define UNITS    512
#define TB       8
#define BLOCK    256

__global__ __launch_bounds__(BLOCK) void prodw_kernel(
    const float* __restrict__ x,   // [B, IN_DIM]
    const float* __restrict__ w,   // [IN_DIM, UNITS]
    float* __restrict__ out)       // [B, UNITS]
{
    const int u  = blockIdx.x * BLOCK + threadIdx.x;  // unit (lane-varying)
    const int b0 = blockIdx.y * TB;                   // batch tile (uniform)

    const float* __restrict__ xrow = x + (size_t)b0 * IN_DIM;
    const float* __restrict__ wu   = w + u;

    v2f pp[TB];  // per-row accumulator pair (i-even, i-odd partial products)
#pragma unroll
    for (int j = 0; j < TB; ++j) pp[j] = (v2f){1.0f, 1.0f};

    // ---- prefetch group 0 ----
    float w0 = wu[0 * UNITS];
    float w1 = wu[1 * UNITS];
    float w2 = wu[2 * UNITS];
    float w3 = wu[3 * UNITS];
    float4 xq[TB];
#pragma unroll
    for (int j = 0; j < TB; ++j)
        xq[j] = *(const float4*)(xrow + j * IN_DIM);   // uniform -> s_load_dwordx4

    // ---- 63 pipelined groups ----
    for (int g = 0; g < IN_DIM / 4 - 1; ++g) {
        const int i4 = g * 4;

        // prefetch next group (w: vector dword loads; x: scalar loads)
        const float* __restrict__ wn = wu + (size_t)(i4 + 4) * UNITS;
        const float n0 = wn[0 * UNITS];
        const float n1 = wn[1 * UNITS];
        const float n2 = wn[2 * UNITS];
        const float n3 = wn[3 * UNITS];
        float4 xn[TB];
#pragma unroll
        for (int j = 0; j < TB; ++j)
            xn[j] = *(const float4*)(xrow + j * IN_DIM + i4 + 4);

        // compute current group with packed fp32
        const v2f wv01 = {w0, w1};
        const v2f wv23 = {w2, w3};
        const v2f c01  = (v2f){1.0f, 1.0f} - wv01;   // pk sub
        const v2f c23  = (v2f){1.0f, 1.0f} - wv23;
#pragma unroll
        for (int j = 0; j < TB; ++j) {
            const v2f x01 = {xq[j].x, xq[j].y};
            const v2f x23 = {xq[j].z, xq[j].w};
            const v2f t01 = __builtin_elementwise_fma(x01, wv01, c01); // v_pk_fma_f32
            const v2f t23 = __builtin_elementwise_fma(x23, wv23, c23);
            pp[j] *= t01 * t23;                                        // 2x v_pk_mul_f32
        }

        w0 = n0; w1 = n1; w2 = n2; w3 = n3;
#pragma unroll
        for (int j = 0; j < TB; ++j) xq[j] = xn[j];
    }

    // ---- epilogue group (i4 = IN_DIM-4) ----
    {
        const v2f wv01 = {w0, w1};
        const v2f wv23 = {w2, w3};
        const v2f c01  = (v2f){1.0f, 1.0f} - wv01;
        const v2f c23  = (v2f){1.0f, 1.0f} - wv23;
#pragma unroll
        for (int j = 0; j < TB; ++j) {
            const v2f x01 = {xq[j].x, xq[j].y};
            const v2f x23 = {xq[j].z, xq[j].w};
            const v2f t01 = __builtin_elementwise_fma(x01, wv01, c01);
            const v2f t23 = __builtin_elementwise_fma(x23, wv23, c23);
            pp[j] *= t01 * t23;
        }
    }

    // ---- fold pairs and store (coalesced dword per row) ----
#pragma unroll
    for (int j = 0; j < TB; ++j)
        out[(size_t)(b0 + j) * UNITS + u] = pp[j].x * pp[j].y;
}

extern "C" void kernel_launch(void* const* d_in, const int* in_sizes, int n_in,
                              void* d_out, int out_size, void* d_ws, size_t ws_size,
                              hipStream_t stream) {
    const float* x = (const float*)d_in[0];        // 2048*256
    const float* w = (const float*)d_in[1];        // 256*512
    float* out     = (float*)d_out;                // 2048*512

    dim3 grid(UNITS / BLOCK, B_DIM / TB);          // (2, 256) = 512 blocks
    dim3 block(BLOCK);
    prodw_kernel<<<grid, block, 0, stream>>>(x, w, out);
}